// Round 1
// baseline (296.629 us; speedup 1.0000x reference)
//
#include <hip/hip_runtime.h>

#define LOG2E 1.4426950408889634f

constexpr int Dn = 128;
constexpr int Nn = 16384;
constexpr int Kn = 64;
constexpr int Bn = 16;

// Prep: one block per k (64 blocks x 64 threads = 1 wave).
// Folds: mu L2-normalize, sigma_inv = exp(-log_sigma), the -2 factor, the
// k-constant (mu_term + log_alpha - 0.5*log_sigma_sum), and log2(e) so the
// main kernel can use exp2. Weight layout: float4 {w1[2d], w2[2d], w1[2d+1], w2[2d+1]}.
__global__ __launch_bounds__(64) void gmm_prep(const float* __restrict__ mu,
                                               const float* __restrict__ log_sigma,
                                               const float* __restrict__ log_alpha,
                                               float4* __restrict__ wout,
                                               float* __restrict__ cout) {
    const int k = blockIdx.x;
    const int l = threadIdx.x;
    const int d0 = 2 * l;
    float m0 = mu[k * Dn + d0];
    float m1 = mu[k * Dn + d0 + 1];
    float s0 = log_sigma[k * Dn + d0];
    float s1 = log_sigma[k * Dn + d0 + 1];
    float nrm2 = m0 * m0 + m1 * m1;
    float lss = s0 + s1;
    #pragma unroll
    for (int off = 32; off > 0; off >>= 1) {
        nrm2 += __shfl_xor(nrm2, off);
        lss  += __shfl_xor(lss, off);
    }
    const float inv_nrm = 1.0f / fmaxf(sqrtf(nrm2), 1e-12f);
    const float mn0 = m0 * inv_nrm, mn1 = m1 * inv_nrm;
    const float si0 = expf(-s0), si1 = expf(-s1);
    float mt = mn0 * mn0 * si0 + mn1 * mn1 * si1;
    #pragma unroll
    for (int off = 32; off > 0; off >>= 1) mt += __shfl_xor(mt, off);
    wout[k * (Dn / 2) + l] = make_float4(-si0 * LOG2E, 2.0f * mn0 * si0 * LOG2E,
                                         -si1 * LOG2E, 2.0f * mn1 * si1 * LOG2E);
    if (l == 0) cout[k] = (log_alpha[k] - 0.5f * lss - mt) * LOG2E;
}

// Main: grid (N/512, B), 512 threads. Thread = (k-half, lane): owns 32 k's for
// n = n0+lane and n0+lane+256. Weights broadcast from LDS (1 ds_read_b128 per
// 8 FMA -> VALU-bound). Softmax across the two k-halves via LDS max/sum
// exchange; exp in log2 domain.
__global__ __launch_bounds__(512, 4) void gmm_main(const float* __restrict__ x,
                                                   const float4* __restrict__ w,
                                                   const float* __restrict__ cks,
                                                   float* __restrict__ out) {
    __shared__ float4 sW[Kn * (Dn / 2)];   // 64 KB
    __shared__ float sC[Kn];
    __shared__ float sMax[2][2][256];      // 4 KB
    __shared__ float sSum[2][2][256];      // 4 KB

    for (int i = threadIdx.x; i < Kn * (Dn / 2); i += 512) sW[i] = w[i];
    if (threadIdx.x < Kn) sC[threadIdx.x] = cks[threadIdx.x];
    __syncthreads();

    const int b = blockIdx.y;
    const int n0 = blockIdx.x * 512;
    const int half = threadIdx.x >> 8;     // which 32-k slice
    const int lane = threadIdx.x & 255;
    const int kbase = half * 32;

    const float* xp = x + (size_t)b * Dn * Nn + n0 + lane;

    float2 acc[32];
    #pragma unroll
    for (int k = 0; k < 32; ++k) acc[k] = make_float2(0.0f, 0.0f);

    for (int dh = 0; dh < Dn / 2; ++dh) {
        const float xa0 = xp[0];
        const float xb0 = xp[256];
        const float xa1 = xp[Nn];
        const float xb1 = xp[Nn + 256];
        xp += 2 * Nn;
        #pragma unroll
        for (int k = 0; k < 32; ++k) {
            const float4 wv = sW[(kbase + k) * (Dn / 2) + dh];
            // logit += x*(x*w1 + w2), two d's, two n's
            const float ta0 = fmaf(xa0, wv.x, wv.y);
            const float tb0 = fmaf(xb0, wv.x, wv.y);
            acc[k].x = fmaf(xa0, ta0, acc[k].x);
            acc[k].y = fmaf(xb0, tb0, acc[k].y);
            const float ta1 = fmaf(xa1, wv.z, wv.w);
            const float tb1 = fmaf(xb1, wv.z, wv.w);
            acc[k].x = fmaf(xa1, ta1, acc[k].x);
            acc[k].y = fmaf(xb1, tb1, acc[k].y);
        }
    }

    // ---- softmax epilogue (log2 domain) ----
    float m0 = -3.0e38f, m1 = -3.0e38f;
    #pragma unroll
    for (int k = 0; k < 32; ++k) {
        const float c = sC[kbase + k];
        acc[k].x += c;
        acc[k].y += c;
        m0 = fmaxf(m0, acc[k].x);
        m1 = fmaxf(m1, acc[k].y);
    }
    sMax[half][0][lane] = m0;
    sMax[half][1][lane] = m1;
    __syncthreads();
    m0 = fmaxf(sMax[0][0][lane], sMax[1][0][lane]);
    m1 = fmaxf(sMax[0][1][lane], sMax[1][1][lane]);

    float s0 = 0.0f, s1 = 0.0f;
    #pragma unroll
    for (int k = 0; k < 32; ++k) {
        acc[k].x = exp2f(acc[k].x - m0);
        acc[k].y = exp2f(acc[k].y - m1);
        s0 += acc[k].x;
        s1 += acc[k].y;
    }
    sSum[half][0][lane] = s0;
    sSum[half][1][lane] = s1;
    __syncthreads();
    const float r0 = 1.0f / (sSum[0][0][lane] + sSum[1][0][lane]);
    const float r1 = 1.0f / (sSum[0][1][lane] + sSum[1][1][lane]);

    float* op = out + (size_t)(b * Kn + kbase) * Nn + n0 + lane;
    #pragma unroll
    for (int k = 0; k < 32; ++k) {
        op[k * Nn] = acc[k].x * r0;
        op[k * Nn + 256] = acc[k].y * r1;
    }
}

extern "C" void kernel_launch(void* const* d_in, const int* in_sizes, int n_in,
                              void* d_out, int out_size, void* d_ws, size_t ws_size,
                              hipStream_t stream) {
    const float* x  = (const float*)d_in[0];
    const float* mu = (const float*)d_in[1];
    const float* ls = (const float*)d_in[2];
    const float* la = (const float*)d_in[3];
    float* out = (float*)d_out;

    float4* wbuf = (float4*)d_ws;
    float*  cbuf = (float*)((char*)d_ws + (size_t)Kn * (Dn / 2) * sizeof(float4));

    gmm_prep<<<dim3(Kn), dim3(64), 0, stream>>>(mu, ls, la, wbuf, cbuf);
    gmm_main<<<dim3(Nn / 512, Bn), dim3(512), 0, stream>>>(x, wbuf, cbuf, out);
}